// Round 12
// baseline (249.772 us; speedup 1.0000x reference)
//
#include <hip/hip_runtime.h>
#include <math.h>

#define B_    512
#define N_    32
#define H_    128
#define KRANK 3
#define PSTEPS 10
#define TSTEPS 100

typedef __attribute__((ext_vector_type(4))) float f32x4;
typedef __attribute__((ext_vector_type(8))) short bf16x8;
typedef __attribute__((ext_vector_type(4))) unsigned short u16x4;

__device__ __forceinline__ unsigned short bf16_rne(float x) {
    unsigned int u = __float_as_uint(x);
    u += 0x7FFFu + ((u >> 16) & 1u);
    return (unsigned short)(u >> 16);
}

// tanh for x >= 0 via hardware exp/rcp: 1 - 2/(e^{2x}+1)
__device__ __forceinline__ float tanh_pos_fast(float x) {
    float e = __expf(2.f * x);
    return 1.f - 2.f * __builtin_amdgcn_rcpf(e + 1.f);
}

// ---------------- kprep: pack W1 hi/lo into per-lane MFMA B-fragment order ----------------
// frag f = bk*8+nf: bk 0..3 = hi blocks, bk 4..7 = lo blocks; element (f, lane, i)
__global__ void kprep_w(const float* __restrict__ W1, unsigned short* __restrict__ Wpk) {
    int t = blockIdx.x * 256 + threadIdx.x;   // 4096 threads
    int lane = t & 63, nf = (t >> 6) & 7, bk = t >> 9;
    int n = nf * 16 + (lane & 15);
    int kbase = (bk & 3) * 32 + (lane >> 4) * 8;
    u16x4 o0, o1;
    #pragma unroll
    for (int i = 0; i < 8; ++i) {
        float w = W1[(kbase + i) * H_ + n];
        unsigned short hi = bf16_rne(w);
        unsigned short v;
        if (bk < 4) v = hi;
        else        v = bf16_rne(w - __uint_as_float((unsigned int)hi << 16));
        if (i < 4) o0[i] = v; else o1[i - 4] = v;
    }
    u16x4* dst = (u16x4*)(Wpk + (long)t * 8);
    dst[0] = o0;
    dst[1] = o1;
}

// ---------------- K1: fused 2-layer MLP, LDS-free, per-wave 16-edge tile ----------------
// Double-buffered B prefetch: group g+1's 8 fragment loads issue before group g's MFMAs.
// Accumulation order bit-identical to R11 (pass-major: Ahi*Bhi kf0..3, Alo*Bhi kf0..3,
// Ahi*Blo kf0..3). Live arch regs ~105 < the 128-arch cap at (256,2) -> no spill.
#define LOADB(buf, base, ptr) \
    { _Pragma("unroll") \
      for (int nf = 0; nf < 8; ++nf) \
          buf[nf] = *(const bf16x8*)((ptr) + (((base) + nf) * 64 + lane) * 8); }

#define MFMAG(afrag, buf) \
    { _Pragma("unroll") \
      for (int nf = 0; nf < 8; ++nf) \
          acc[nf] = __builtin_amdgcn_mfma_f32_16x16x32_bf16(afrag, buf[nf], acc[nf], 0, 0, 0); }

__global__ __launch_bounds__(256, 2) void k1_mlp(
    const float* __restrict__ e, const unsigned short* __restrict__ Wpk,
    const float* __restrict__ b1, const float* __restrict__ W2,
    const float* __restrict__ b2,
    float* __restrict__ r0, float* __restrict__ r1) {

    int tid = threadIdx.x;
    int w = tid >> 6, lane = tid & 63;
    int mrow = lane & 15, kq = lane >> 4;          // kq = k-quarter 0..3
    long ebase = ((long)blockIdx.x * 4 + w) * 16;  // this wave's 16-edge tile

    bf16x8 bA[8], bB[8];
    // issue first two B groups early: latency hides under the A-build VALU below
    LOADB(bA, 0, Wpk);
    LOADB(bB, 8, Wpk);

    // ---- build A fragments once: hi = rne(e), lo = rne(e - hi) ----
    bf16x8 ahi[4], alo[4];
    #pragma unroll
    for (int kf = 0; kf < 4; ++kf) {
        const float* ap = e + (ebase + mrow) * H_ + kf * 32 + kq * 8;
        f32x4 v0 = *(const f32x4*)ap;
        f32x4 v1 = *(const f32x4*)(ap + 4);
        bf16x8 h, l;
        #pragma unroll
        for (int q = 0; q < 4; ++q) {
            unsigned short h0 = bf16_rne(v0[q]);
            h[q] = (short)h0;
            l[q] = (short)bf16_rne(v0[q] - __uint_as_float((unsigned int)h0 << 16));
            unsigned short h1 = bf16_rne(v1[q]);
            h[q + 4] = (short)h1;
            l[q + 4] = (short)bf16_rne(v1[q] - __uint_as_float((unsigned int)h1 << 16));
        }
        ahi[kf] = h;
        alo[kf] = l;
    }

    // ---- init accumulators with b1 ----
    f32x4 acc[8];
    #pragma unroll
    for (int nf = 0; nf < 8; ++nf) {
        float bv = b1[nf * 16 + mrow];
        acc[nf] = (f32x4){bv, bv, bv, bv};
    }

    // ---- pipelined 12-group main chain (order = R11 pass-major, bit-identical) ----
    const unsigned short* Wpk2 = Wpk;    // opaque alias: stops CSE of pass-2 reloads
    asm("" : "+v"(Wpk2));

    MFMAG(ahi[0], bA); LOADB(bA, 16, Wpk);    // compute g0 | prefetch g2
    MFMAG(ahi[1], bB); LOADB(bB, 24, Wpk);    // g1 | g3
    MFMAG(ahi[2], bA); LOADB(bA, 0,  Wpk2);   // g2 | g4 (pass 2, Bhi kf0)
    MFMAG(ahi[3], bB); LOADB(bB, 8,  Wpk2);   // g3 | g5
    MFMAG(alo[0], bA); LOADB(bA, 16, Wpk2);   // g4 | g6
    MFMAG(alo[1], bB); LOADB(bB, 24, Wpk2);   // g5 | g7
    MFMAG(alo[2], bA); LOADB(bA, 32, Wpk);    // g6 | g8 (pass 3, Blo kf0)
    MFMAG(alo[3], bB); LOADB(bB, 40, Wpk);    // g7 | g9
    MFMAG(ahi[0], bA); LOADB(bA, 48, Wpk);    // g8 | g10
    MFMAG(ahi[1], bB); LOADB(bB, 56, Wpk);    // g9 | g11
    MFMAG(ahi[2], bA);                        // g10
    MFMAG(ahi[3], bB);                        // g11

    // ---- layer 2 epilogue: relu, W2, 16-lane reduce, store ----
    float w2a[8], w2b[8];
    #pragma unroll
    for (int nf = 0; nf < 8; ++nf) {
        int j = nf * 16 + mrow;
        w2a[nf] = W2[j * 2];
        w2b[nf] = W2[j * 2 + 1];
    }
    float bb0 = b2[0], bb1 = b2[1];
    #pragma unroll
    for (int r = 0; r < 4; ++r) {
        float p0 = 0.f, p1 = 0.f;
        #pragma unroll
        for (int nf = 0; nf < 8; ++nf) {
            float hv = fmaxf(acc[nf][r], 0.f);
            p0 = fmaf(hv, w2a[nf], p0);
            p1 = fmaf(hv, w2b[nf], p1);
        }
        #pragma unroll
        for (int d = 1; d < 16; d <<= 1) {
            p0 += __shfl_xor(p0, d);
            p1 += __shfl_xor(p1, d);
        }
        if (mrow == 0) {
            long edge = ebase + kq * 4 + r;
            r0[edge] = p0 + bb0;
            r1[edge] = p1 + bb1;
        }
    }
}

// ---------------- K2: symmetrize + softplus, in place over pairs (i<=j) ----------------
__device__ __forceinline__ float softplusf(float x) {
    return x > 20.f ? x : log1pf(expf(x));
}

__global__ void k2_sym(float* __restrict__ r0, float* __restrict__ r1) {
    int t = blockIdx.x * 256 + threadIdx.x;    // 512 * 528 = 270336 pairs
    int b = t / 528, r = t % 528;
    float disc = sqrtf((float)(4225 - 8 * r));
    int i = (int)((65.f - disc) * 0.5f);
    int j = r - (i * (65 - i)) / 2 + i;
    int base = b * 1024;
    int ij = base + i * 32 + j;
    int ji = base + j * 32 + i;
    float s0 = r0[ij] + r0[ji];
    float s1 = r1[ij] + r1[ji];
    float Dv = (i == j) ? 0.f : softplusf(s0);
    float Wv = softplusf(s1);
    r0[ij] = Dv; r0[ji] = Dv;
    r1[ij] = Wv; r1[ji] = Wv;
}

// ---------------- K3: 2 waves per batch, ping-pong X, fast-math chain ----------------
__global__ __launch_bounds__(128) void k3_solve(
    const float* __restrict__ Dg, const float* __restrict__ Wg,
    const float* __restrict__ noise, const float* __restrict__ u_init,
    float* __restrict__ Xout) {
    int b = blockIdx.x;
    int tid = threadIdx.x;          // 0..127

    __shared__ float Ds[32][33];
    __shared__ float Ws_[32][33];
    __shared__ float Gs[32][33];
    __shared__ float Xb[2][32][5];

    const float* Db = Dg + b * 1024;
    const float* Wb = Wg + b * 1024;
    #pragma unroll 1
    for (int s = 0; s < 8; ++s) {
        int idx = s * 128 + tid;
        int i = idx >> 5, j = idx & 31;
        Ds[i][j]  = Db[idx];
        Ws_[i][j] = Wb[idx];
    }
    __syncthreads();

    // G = D^T D
    #pragma unroll 1
    for (int s = 0; s < 8; ++s) {
        int idx = s * 128 + tid;
        int i = idx >> 5, j = idx & 31;
        float acc = 0.f;
        #pragma unroll
        for (int k = 0; k < 32; ++k) acc = fmaf(Ds[k][i], Ds[k][j], acc);
        Gs[i][j] = acc;
    }
    __syncthreads();

    int w = tid >> 6, lane = tid & 63;
    int il = lane & 15;
    int i = w * 16 + il;
    int jq = lane >> 4;
    float Drow[8], Wrow[8];
    #pragma unroll
    for (int jj = 0; jj < 8; ++jj) {
        int j = jq * 8 + jj;
        Drow[jj] = Ds[i][j];
        Wrow[jj] = Ws_[i][j];
    }

    if (tid < 32) {
        int l = tid;
        float Arow[32];
        #pragma unroll
        for (int j = 0; j < 32; ++j) Arow[j] = Gs[l][j];
        float x0 = 0.f, x1 = 0.f, x2 = 0.f;
        for (int s = 0; s < KRANK; ++s) {
            float u = u_init[((long)s * B_ + b) * 32 + l];
            for (int p = 0; p < PSTEPS; ++p) {
                float red = u * u;
                #pragma unroll
                for (int m = 1; m < 32; m <<= 1) red += __shfl_xor(red, m, 32);
                float un = u * __builtin_amdgcn_rcpf(fmaxf(__builtin_amdgcn_sqrtf(red), 1e-3f));
                float acc = 0.f;
                #pragma unroll
                for (int j = 0; j < 32; ++j) acc = fmaf(Arow[j], __shfl(un, j, 32), acc);
                u = acc;
            }
            float red = u * u;
            #pragma unroll
            for (int m = 1; m < 32; m <<= 1) red += __shfl_xor(red, m, 32);
            float sc = __builtin_amdgcn_sqrtf(__builtin_amdgcn_sqrtf(red + 0.01f));
            u *= sc;
            if (s == 0) x0 = u; else if (s == 1) x1 = u; else x2 = u;
            #pragma unroll
            for (int j = 0; j < 32; ++j) Arow[j] = fmaf(-u, __shfl(u, j, 32), Arow[j]);
        }
        const float* nb = noise + ((long)b * 32 + l) * 3;
        Xb[0][l][0] = x0 + nb[0];
        Xb[0][l][1] = x1 + nb[1];
        Xb[0][l][2] = x2 + nb[2];
    }
    __syncthreads();

    #pragma unroll 1
    for (int t = 0; t < TSTEPS; ++t) {
        int rb = t & 1;
        float a_t = 0.1f + 4.9f * (float)(TSTEPS - t) / (float)TSTEPS;
        float ra  = __builtin_amdgcn_rcpf(a_t);
        float xi0 = Xb[rb][i][0], xi1 = Xb[rb][i][1], xi2 = Xb[rb][i][2];
        float sc_ = 0.f, s0 = 0.f, s1 = 0.f, s2 = 0.f;
        #pragma unroll
        for (int jj = 0; jj < 8; ++jj) {
            int j = jq * 8 + jj;
            float xj0 = Xb[rb][j][0], xj1 = Xb[rb][j][1], xj2 = Xb[rb][j][2];
            float dx = xi0 - xj0, dy = xi1 - xj1, dz = xi2 - xj2;
            float dd = fmaf(dx, dx, fmaf(dy, dy, fmaf(dz, dz, 0.01f)));
            float c = -4.f * Wrow[jj] * fmaf(Drow[jj], __builtin_amdgcn_rsqf(dd), -1.f);
            sc_ += c;
            s0 = fmaf(c, xj0, s0);
            s1 = fmaf(c, xj1, s1);
            s2 = fmaf(c, xj2, s2);
        }
        sc_ += __shfl_xor(sc_, 16); s0 += __shfl_xor(s0, 16);
        s1  += __shfl_xor(s1, 16);  s2 += __shfl_xor(s2, 16);
        sc_ += __shfl_xor(sc_, 32); s0 += __shfl_xor(s0, 32);
        s1  += __shfl_xor(s1, 32);  s2 += __shfl_xor(s2, 32);
        if (jq == 0) {
            float d0 = -0.1f * fmaf(xi0, sc_, -s0);
            float d1 = -0.1f * fmaf(xi1, sc_, -s1);
            float d2 = -0.1f * fmaf(xi2, sc_, -s2);
            float sd = fmaf(d0, d0, fmaf(d1, d1, fmaf(d2, d2, 1e-3f)));
            float rs = __builtin_amdgcn_rsqf(sd);
            float arg = sd * rs * ra;
            float scale = a_t * tanh_pos_fast(arg) * rs;
            Xb[rb ^ 1][i][0] = fmaf(d0, scale, xi0);
            Xb[rb ^ 1][i][1] = fmaf(d1, scale, xi1);
            Xb[rb ^ 1][i][2] = fmaf(d2, scale, xi2);
        }
        __syncthreads();
    }

    if (tid < 32) {
        float* xo = Xout + ((long)b * 32 + tid) * 3;
        xo[0] = Xb[0][tid][0];
        xo[1] = Xb[0][tid][1];
        xo[2] = Xb[0][tid][2];
    }
}

extern "C" void kernel_launch(void* const* d_in, const int* in_sizes, int n_in,
                              void* d_out, int out_size, void* d_ws, size_t ws_size,
                              hipStream_t stream) {
    const float* e      = (const float*)d_in[0];
    const float* W1     = (const float*)d_in[1];
    const float* b1     = (const float*)d_in[2];
    const float* W2     = (const float*)d_in[3];
    const float* b2     = (const float*)d_in[4];
    const float* noise  = (const float*)d_in[5];
    const float* u_init = (const float*)d_in[6];
    float* out = (float*)d_out;

    unsigned short* Wpk = (unsigned short*)d_ws;   // 64 KB packed W1 hi/lo fragments

    float* r0 = out;             // D region, used first as raw ch0
    float* r1 = out + 524288;    // W region, used first as raw ch1
    float* X  = out + 1048576;   // X_pred region

    hipLaunchKernelGGL(kprep_w, dim3(16),   dim3(256), 0, stream, W1, Wpk);
    hipLaunchKernelGGL(k1_mlp,  dim3(8192), dim3(256), 0, stream, e, Wpk, b1, W2, b2, r0, r1);
    hipLaunchKernelGGL(k2_sym,  dim3(1056), dim3(256), 0, stream, r0, r1);
    hipLaunchKernelGGL(k3_solve, dim3(512), dim3(128), 0, stream, r0, r1, noise, u_init, X);
}

// Round 13
// 239.431 us; speedup vs baseline: 1.0432x; 1.0432x over previous
//
#include <hip/hip_runtime.h>
#include <math.h>

#define B_    512
#define N_    32
#define H_    128
#define KRANK 3
#define PSTEPS 10
#define TSTEPS 100

typedef __attribute__((ext_vector_type(4))) float f32x4;
typedef __attribute__((ext_vector_type(8))) short bf16x8;
typedef __attribute__((ext_vector_type(4))) unsigned short u16x4;

__device__ __forceinline__ unsigned short bf16_rne(float x) {
    unsigned int u = __float_as_uint(x);
    u += 0x7FFFu + ((u >> 16) & 1u);
    return (unsigned short)(u >> 16);
}

// tanh for x >= 0 via hardware exp/rcp: 1 - 2/(e^{2x}+1)
__device__ __forceinline__ float tanh_pos_fast(float x) {
    float e = __expf(2.f * x);
    return 1.f - 2.f * __builtin_amdgcn_rcpf(e + 1.f);
}

// ---------------- kprep: pack W1 hi/lo into per-lane MFMA B-fragment order ----------------
// frag f = bk*8+nf: bk 0..3 = hi blocks, bk 4..7 = lo blocks; element (f, lane, i)
__global__ void kprep_w(const float* __restrict__ W1, unsigned short* __restrict__ Wpk) {
    int t = blockIdx.x * 256 + threadIdx.x;   // 4096 threads
    int lane = t & 63, nf = (t >> 6) & 7, bk = t >> 9;
    int n = nf * 16 + (lane & 15);
    int kbase = (bk & 3) * 32 + (lane >> 4) * 8;
    u16x4 o0, o1;
    #pragma unroll
    for (int i = 0; i < 8; ++i) {
        float w = W1[(kbase + i) * H_ + n];
        unsigned short hi = bf16_rne(w);
        unsigned short v;
        if (bk < 4) v = hi;
        else        v = bf16_rne(w - __uint_as_float((unsigned int)hi << 16));
        if (i < 4) o0[i] = v; else o1[i - 4] = v;
    }
    u16x4* dst = (u16x4*)(Wpk + (long)t * 8);
    dst[0] = o0;
    dst[1] = o1;
}

// ---------------- K1: fused 2-layer MLP, 32-edge wave tile, AGPR accumulators ----------------
// Inline-asm MFMA with "+a" forces acc into AGPRs: arch live set = ahi 32 + alo 32 +
// transient bfr 32 + addr ~ 110 < 128-arch cap at (256,2) -> no spill, half the B bytes
// per edge vs the 16-edge tile. Numerics bit-identical to R11/R12: RNE hi/lo, per-element
// pass-major order (Ahi*Bhi kf0..3, Alo*Bhi kf0..3, Ahi*Blo kf0..3).
#define MFMA_A(accv, av, bv) \
    asm("v_mfma_f32_16x16x32_bf16 %0, %1, %2, %0" : "+a"(accv) : "v"(av), "v"(bv))

#define LOADB(buf, base, ptr) \
    { _Pragma("unroll") \
      for (int nf = 0; nf < 8; ++nf) \
          buf[nf] = *(const bf16x8*)((ptr) + (((base) + nf) * 64 + lane) * 8); }

#define GROUP(a0, a1, base, ptr) { \
    bf16x8 bfr[8]; \
    LOADB(bfr, base, ptr); \
    _Pragma("unroll") \
    for (int nf = 0; nf < 8; ++nf) MFMA_A(acc[0][nf], a0, bfr[nf]); \
    _Pragma("unroll") \
    for (int nf = 0; nf < 8; ++nf) MFMA_A(acc[1][nf], a1, bfr[nf]); }

__global__ __launch_bounds__(256, 2) void k1_mlp(
    const float* __restrict__ e, const unsigned short* __restrict__ Wpk,
    const float* __restrict__ b1, const float* __restrict__ W2,
    const float* __restrict__ b2,
    float* __restrict__ r0, float* __restrict__ r1) {

    int tid = threadIdx.x;
    int w = tid >> 6, lane = tid & 63;
    int mrow = lane & 15, kq = lane >> 4;          // kq = k-quarter 0..3
    long ebase = ((long)blockIdx.x * 4 + w) * 32;  // this wave's 32-edge tile

    // ---- build A fragments once: hi = rne(e), lo = rne(e - hi) ----
    bf16x8 ahi[2][4], alo[2][4];
    #pragma unroll
    for (int mf = 0; mf < 2; ++mf) {
        #pragma unroll
        for (int kf = 0; kf < 4; ++kf) {
            const float* ap = e + (ebase + mf * 16 + mrow) * H_ + kf * 32 + kq * 8;
            f32x4 v0 = *(const f32x4*)ap;
            f32x4 v1 = *(const f32x4*)(ap + 4);
            bf16x8 h, l;
            #pragma unroll
            for (int q = 0; q < 4; ++q) {
                unsigned short h0 = bf16_rne(v0[q]);
                h[q] = (short)h0;
                l[q] = (short)bf16_rne(v0[q] - __uint_as_float((unsigned int)h0 << 16));
                unsigned short h1 = bf16_rne(v1[q]);
                h[q + 4] = (short)h1;
                l[q + 4] = (short)bf16_rne(v1[q] - __uint_as_float((unsigned int)h1 << 16));
            }
            ahi[mf][kf] = h;
            alo[mf][kf] = l;
        }
    }

    // ---- init accumulators with b1 (compiler emits accvgpr_write) ----
    f32x4 acc[2][8];
    #pragma unroll
    for (int nf = 0; nf < 8; ++nf) {
        float bv = b1[nf * 16 + mrow];
        acc[0][nf] = (f32x4){bv, bv, bv, bv};
        acc[1][nf] = acc[0][nf];
    }

    // ---- 12-group chain, pass-major, bit-identical per-element order ----
    const unsigned short* Wpk2 = Wpk;    // opaque alias: stops CSE of pass-2 reloads
    asm("" : "+v"(Wpk2));

    // pass 1: Ahi * Bhi
    GROUP(ahi[0][0], ahi[1][0],  0, Wpk);
    GROUP(ahi[0][1], ahi[1][1],  8, Wpk);
    GROUP(ahi[0][2], ahi[1][2], 16, Wpk);
    GROUP(ahi[0][3], ahi[1][3], 24, Wpk);
    // pass 2: Alo * Bhi (reloaded via opaque pointer)
    GROUP(alo[0][0], alo[1][0],  0, Wpk2);
    GROUP(alo[0][1], alo[1][1],  8, Wpk2);
    GROUP(alo[0][2], alo[1][2], 16, Wpk2);
    GROUP(alo[0][3], alo[1][3], 24, Wpk2);
    // pass 3: Ahi * Blo
    GROUP(ahi[0][0], ahi[1][0], 32, Wpk);
    GROUP(ahi[0][1], ahi[1][1], 40, Wpk);
    GROUP(ahi[0][2], ahi[1][2], 48, Wpk);
    GROUP(ahi[0][3], ahi[1][3], 56, Wpk);

    // ---- layer 2 epilogue: relu, W2, 16-lane reduce, store ----
    float w2a[8], w2b[8];
    #pragma unroll
    for (int nf = 0; nf < 8; ++nf) {
        int j = nf * 16 + mrow;
        w2a[nf] = W2[j * 2];
        w2b[nf] = W2[j * 2 + 1];
    }
    float bb0 = b2[0], bb1 = b2[1];
    #pragma unroll
    for (int mf = 0; mf < 2; ++mf) {
        #pragma unroll
        for (int r = 0; r < 4; ++r) {
            float p0 = 0.f, p1 = 0.f;
            #pragma unroll
            for (int nf = 0; nf < 8; ++nf) {
                float hv = fmaxf(acc[mf][nf][r], 0.f);
                p0 = fmaf(hv, w2a[nf], p0);
                p1 = fmaf(hv, w2b[nf], p1);
            }
            #pragma unroll
            for (int d = 1; d < 16; d <<= 1) {
                p0 += __shfl_xor(p0, d);
                p1 += __shfl_xor(p1, d);
            }
            if (mrow == 0) {
                long edge = ebase + mf * 16 + kq * 4 + r;
                r0[edge] = p0 + bb0;
                r1[edge] = p1 + bb1;
            }
        }
    }
}

// ---------------- K2: symmetrize + softplus, in place over pairs (i<=j) ----------------
__device__ __forceinline__ float softplusf(float x) {
    return x > 20.f ? x : log1pf(expf(x));
}

__global__ void k2_sym(float* __restrict__ r0, float* __restrict__ r1) {
    int t = blockIdx.x * 256 + threadIdx.x;    // 512 * 528 = 270336 pairs
    int b = t / 528, r = t % 528;
    float disc = sqrtf((float)(4225 - 8 * r));
    int i = (int)((65.f - disc) * 0.5f);
    int j = r - (i * (65 - i)) / 2 + i;
    int base = b * 1024;
    int ij = base + i * 32 + j;
    int ji = base + j * 32 + i;
    float s0 = r0[ij] + r0[ji];
    float s1 = r1[ij] + r1[ji];
    float Dv = (i == j) ? 0.f : softplusf(s0);
    float Wv = softplusf(s1);
    r0[ij] = Dv; r0[ji] = Dv;
    r1[ij] = Wv; r1[ji] = Wv;
}

// ---------------- K3: 2 waves per batch, ping-pong X, fast-math chain ----------------
__global__ __launch_bounds__(128) void k3_solve(
    const float* __restrict__ Dg, const float* __restrict__ Wg,
    const float* __restrict__ noise, const float* __restrict__ u_init,
    float* __restrict__ Xout) {
    int b = blockIdx.x;
    int tid = threadIdx.x;          // 0..127

    __shared__ float Ds[32][33];
    __shared__ float Ws_[32][33];
    __shared__ float Gs[32][33];
    __shared__ float Xb[2][32][5];

    const float* Db = Dg + b * 1024;
    const float* Wb = Wg + b * 1024;
    #pragma unroll 1
    for (int s = 0; s < 8; ++s) {
        int idx = s * 128 + tid;
        int i = idx >> 5, j = idx & 31;
        Ds[i][j]  = Db[idx];
        Ws_[i][j] = Wb[idx];
    }
    __syncthreads();

    // G = D^T D
    #pragma unroll 1
    for (int s = 0; s < 8; ++s) {
        int idx = s * 128 + tid;
        int i = idx >> 5, j = idx & 31;
        float acc = 0.f;
        #pragma unroll
        for (int k = 0; k < 32; ++k) acc = fmaf(Ds[k][i], Ds[k][j], acc);
        Gs[i][j] = acc;
    }
    __syncthreads();

    int w = tid >> 6, lane = tid & 63;
    int il = lane & 15;
    int i = w * 16 + il;
    int jq = lane >> 4;
    float Drow[8], Wrow[8];
    #pragma unroll
    for (int jj = 0; jj < 8; ++jj) {
        int j = jq * 8 + jj;
        Drow[jj] = Ds[i][j];
        Wrow[jj] = Ws_[i][j];
    }

    if (tid < 32) {
        int l = tid;
        float Arow[32];
        #pragma unroll
        for (int j = 0; j < 32; ++j) Arow[j] = Gs[l][j];
        float x0 = 0.f, x1 = 0.f, x2 = 0.f;
        for (int s = 0; s < KRANK; ++s) {
            float u = u_init[((long)s * B_ + b) * 32 + l];
            for (int p = 0; p < PSTEPS; ++p) {
                float red = u * u;
                #pragma unroll
                for (int m = 1; m < 32; m <<= 1) red += __shfl_xor(red, m, 32);
                float un = u * __builtin_amdgcn_rcpf(fmaxf(__builtin_amdgcn_sqrtf(red), 1e-3f));
                float acc = 0.f;
                #pragma unroll
                for (int j = 0; j < 32; ++j) acc = fmaf(Arow[j], __shfl(un, j, 32), acc);
                u = acc;
            }
            float red = u * u;
            #pragma unroll
            for (int m = 1; m < 32; m <<= 1) red += __shfl_xor(red, m, 32);
            float sc = __builtin_amdgcn_sqrtf(__builtin_amdgcn_sqrtf(red + 0.01f));
            u *= sc;
            if (s == 0) x0 = u; else if (s == 1) x1 = u; else x2 = u;
            #pragma unroll
            for (int j = 0; j < 32; ++j) Arow[j] = fmaf(-u, __shfl(u, j, 32), Arow[j]);
        }
        const float* nb = noise + ((long)b * 32 + l) * 3;
        Xb[0][l][0] = x0 + nb[0];
        Xb[0][l][1] = x1 + nb[1];
        Xb[0][l][2] = x2 + nb[2];
    }
    __syncthreads();

    #pragma unroll 1
    for (int t = 0; t < TSTEPS; ++t) {
        int rb = t & 1;
        float a_t = 0.1f + 4.9f * (float)(TSTEPS - t) / (float)TSTEPS;
        float ra  = __builtin_amdgcn_rcpf(a_t);
        float xi0 = Xb[rb][i][0], xi1 = Xb[rb][i][1], xi2 = Xb[rb][i][2];
        float sc_ = 0.f, s0 = 0.f, s1 = 0.f, s2 = 0.f;
        #pragma unroll
        for (int jj = 0; jj < 8; ++jj) {
            int j = jq * 8 + jj;
            float xj0 = Xb[rb][j][0], xj1 = Xb[rb][j][1], xj2 = Xb[rb][j][2];
            float dx = xi0 - xj0, dy = xi1 - xj1, dz = xi2 - xj2;
            float dd = fmaf(dx, dx, fmaf(dy, dy, fmaf(dz, dz, 0.01f)));
            float c = -4.f * Wrow[jj] * fmaf(Drow[jj], __builtin_amdgcn_rsqf(dd), -1.f);
            sc_ += c;
            s0 = fmaf(c, xj0, s0);
            s1 = fmaf(c, xj1, s1);
            s2 = fmaf(c, xj2, s2);
        }
        sc_ += __shfl_xor(sc_, 16); s0 += __shfl_xor(s0, 16);
        s1  += __shfl_xor(s1, 16);  s2 += __shfl_xor(s2, 16);
        sc_ += __shfl_xor(sc_, 32); s0 += __shfl_xor(s0, 32);
        s1  += __shfl_xor(s1, 32);  s2 += __shfl_xor(s2, 32);
        if (jq == 0) {
            float d0 = -0.1f * fmaf(xi0, sc_, -s0);
            float d1 = -0.1f * fmaf(xi1, sc_, -s1);
            float d2 = -0.1f * fmaf(xi2, sc_, -s2);
            float sd = fmaf(d0, d0, fmaf(d1, d1, fmaf(d2, d2, 1e-3f)));
            float rs = __builtin_amdgcn_rsqf(sd);
            float arg = sd * rs * ra;
            float scale = a_t * tanh_pos_fast(arg) * rs;
            Xb[rb ^ 1][i][0] = fmaf(d0, scale, xi0);
            Xb[rb ^ 1][i][1] = fmaf(d1, scale, xi1);
            Xb[rb ^ 1][i][2] = fmaf(d2, scale, xi2);
        }
        __syncthreads();
    }

    if (tid < 32) {
        float* xo = Xout + ((long)b * 32 + tid) * 3;
        xo[0] = Xb[0][tid][0];
        xo[1] = Xb[0][tid][1];
        xo[2] = Xb[0][tid][2];
    }
}

extern "C" void kernel_launch(void* const* d_in, const int* in_sizes, int n_in,
                              void* d_out, int out_size, void* d_ws, size_t ws_size,
                              hipStream_t stream) {
    const float* e      = (const float*)d_in[0];
    const float* W1     = (const float*)d_in[1];
    const float* b1     = (const float*)d_in[2];
    const float* W2     = (const float*)d_in[3];
    const float* b2     = (const float*)d_in[4];
    const float* noise  = (const float*)d_in[5];
    const float* u_init = (const float*)d_in[6];
    float* out = (float*)d_out;

    unsigned short* Wpk = (unsigned short*)d_ws;   // 64 KB packed W1 hi/lo fragments

    float* r0 = out;             // D region, used first as raw ch0
    float* r1 = out + 524288;    // W region, used first as raw ch1
    float* X  = out + 1048576;   // X_pred region

    hipLaunchKernelGGL(kprep_w, dim3(16),   dim3(256), 0, stream, W1, Wpk);
    hipLaunchKernelGGL(k1_mlp,  dim3(4096), dim3(256), 0, stream, e, Wpk, b1, W2, b2, r0, r1);
    hipLaunchKernelGGL(k2_sym,  dim3(1056), dim3(256), 0, stream, r0, r1);
    hipLaunchKernelGGL(k3_solve, dim3(512), dim3(128), 0, stream, r0, r1, noise, u_init, X);
}